// Round 12
// baseline (35.199 us; speedup 1.0000x reference)
//
#include <hip/hip_runtime.h>

#define N_SP 2304      // H*W = 48*48
#define C_CH 256
#define B_B  8
#define TILES 36       // N_SP / 64
#define BN_EPS 1e-5f
#define K3_REPS 5      // DIAGNOSTIC: repeat K3 body to surface counters

// workspace layout (float offsets)
#define WS_THETA 0                 // 8*2304 = 18432 floats
#define WS_PG    18432             // 288
#define WS_TH    (18432 + 288)     // 288
#define WS_TH2   (18432 + 576)     // 288

// K1: per-(b, 64-n tile) projections. (byte-identical to R4/R7)
__global__ __launch_bounds__(512) void proj_kernel(
    const float* __restrict__ x,
    const float* __restrict__ gw, const float* __restrict__ gb,
    const float* __restrict__ tw, const float* __restrict__ tb,
    const float* __restrict__ pw, const float* __restrict__ pb,
    float* __restrict__ ws)
{
    __shared__ float pt[8][64], pp[8][64], pgv[8][64];

    const int tid  = threadIdx.x;
    const int w    = tid >> 6;
    const int lane = tid & 63;
    const int blk  = blockIdx.x;
    const int b    = blk / TILES;
    const int tile = blk - b * TILES;

    const int n = tile * 64 + lane;
    const int cbase = __builtin_amdgcn_readfirstlane(w * 32);   // SGPR
    const float* xp = x + (size_t)b * C_CH * N_SP + (size_t)cbase * N_SP + n;

    float at = 0.f, ap = 0.f, ag = 0.f;
    #pragma unroll
    for (int c = 0; c < 32; ++c) {
        float v = xp[(size_t)c * N_SP];           // 256B coalesced per wave
        at = fmaf(tw[cbase + c], v, at);          // s_load (scalar cache)
        ap = fmaf(pw[cbase + c], v, ap);
        ag = fmaf(gw[cbase + c], v, ag);
    }
    pt[w][lane]  = at;
    pp[w][lane]  = ap;
    pgv[w][lane] = ag;
    __syncthreads();

    if (tid < 64) {
        float st = 0.f, sp = 0.f, sg = 0.f;
        #pragma unroll
        for (int j = 0; j < 8; ++j) {
            st += pt[j][tid];
            sp += pp[j][tid];
            sg += pgv[j][tid];
        }
        const float th = st + tb[0];
        const float ph = sp + pb[0];
        const float gg = sg + gb[0];

        ws[WS_THETA + b * N_SP + tile * 64 + tid] = th;

        float r_pg  = ph * gg;
        float r_th  = th;
        float r_th2 = th * th;
        #pragma unroll
        for (int off = 32; off >= 1; off >>= 1) {
            r_pg  += __shfl_xor(r_pg,  off, 64);
            r_th  += __shfl_xor(r_th,  off, 64);
            r_th2 += __shfl_xor(r_th2, off, 64);
        }
        if (tid == 0) {
            ws[WS_PG  + blk] = r_pg;
            ws[WS_TH  + blk] = r_th;
            ws[WS_TH2 + blk] = r_th2;
        }
    }
}

// K3: body byte-identical to R7, wrapped in a REPS loop (idempotent —
// every rep computes and stores the identical values). Diagnostic only.
__global__ __launch_bounds__(512) void out_kernel(
    const float* __restrict__ x,  const float* __restrict__ ww,
    const float* __restrict__ gamma, const float* __restrict__ beta,
    const float* __restrict__ ws, float* __restrict__ out)
{
    __shared__ float fS[B_B], fTH[B_B], fTH2[B_B];
    const int tid = threadIdx.x;

    #pragma clang loop unroll(disable)
    for (int rep = 0; rep < K3_REPS; ++rep) {
        __syncthreads();

        // ---- finalize prologue: wave 0 reduces the 3x288 partials ----
        if (tid < 64) {
            const int fb = tid >> 3;        // 8 groups of 8 lanes
            const int l  = tid & 7;
            float pg = 0.f, th = 0.f, th2 = 0.f;
            #pragma unroll
            for (int k = 0; k < 5; ++k) {
                const int t = l + 8 * k;
                if (t < TILES) {
                    pg  += ws[WS_PG  + fb * TILES + t];
                    th  += ws[WS_TH  + fb * TILES + t];
                    th2 += ws[WS_TH2 + fb * TILES + t];
                }
            }
            #pragma unroll
            for (int off = 4; off >= 1; off >>= 1) {
                pg  += __shfl_xor(pg,  off, 64);
                th  += __shfl_xor(th,  off, 64);
                th2 += __shfl_xor(th2, off, 64);
            }
            if (l == 0) {
                fS[fb]   = pg / (float)N_SP;   // s_b
                fTH[fb]  = th;
                fTH2[fb] = th2;
            }
        }
        __syncthreads();

        const int blk  = blockIdx.x;                       // 0..255
        const int b    = blk >> 5;                          // 32 blocks per b
        const int c0   = (blk & 31) * 8;                    // 8 channels per block
        const int w    = __builtin_amdgcn_readfirstlane(tid >> 6);  // wave id
        const int lane = tid & 63;
        const int c    = c0 + w;                            // wave-uniform channel

        float ybar = 0.f, ey2 = 0.f;
        #pragma unroll
        for (int bb = 0; bb < B_B; ++bb) {
            ybar += fS[bb] * fTH[bb];     // LDS broadcast reads
            ey2  += fS[bb] * fS[bb] * fTH2[bb];
        }
        const float inv = 1.0f / (float)(B_B * N_SP);
        ybar *= inv;
        ey2  *= inv;
        const float vary = ey2 - ybar * ybar;

        const float wv = ww[c];          // wave-uniform -> s_load
        const float sc = gamma[c] * wv * rsqrtf(fmaf(wv * wv, vary, BN_EPS));
        const float s  = fS[b];
        const float be = beta[c];
        const float yb = ybar;

        const size_t row = ((size_t)b * C_CH + c) * N_SP;
        const float4* xr   = (const float4*)(x + row);
        const float4* tr   = (const float4*)(ws + WS_THETA + b * N_SP);
        float4*       orow = (float4*)((float*)out + row);

        #pragma unroll
        for (int k = 0; k < 9; ++k) {
            const int i = lane + k * 64;   // 9*64*4 = 2304 floats exactly
            float4 xv = xr[i];
            float4 tv = tr[i];
            float4 o;
            o.x = fmaf(sc, fmaf(tv.x, s, -yb), xv.x + be);
            o.y = fmaf(sc, fmaf(tv.y, s, -yb), xv.y + be);
            o.z = fmaf(sc, fmaf(tv.z, s, -yb), xv.z + be);
            o.w = fmaf(sc, fmaf(tv.w, s, -yb), xv.w + be);
            orow[i] = o;
        }

        asm volatile("" ::: "memory");   // keep reps distinct
    }
}

extern "C" void kernel_launch(void* const* d_in, const int* in_sizes, int n_in,
                              void* d_out, int out_size, void* d_ws, size_t ws_size,
                              hipStream_t stream) {
    const float* x        = (const float*)d_in[0];
    const float* g_w      = (const float*)d_in[1];
    const float* g_b      = (const float*)d_in[2];
    const float* theta_w  = (const float*)d_in[3];
    const float* theta_b  = (const float*)d_in[4];
    const float* phi_w    = (const float*)d_in[5];
    const float* phi_b    = (const float*)d_in[6];
    const float* w_w      = (const float*)d_in[7];
    // d_in[8] = w_b : cancels in training-mode BatchNorm (mean subtraction)
    const float* bn_gamma = (const float*)d_in[9];
    const float* bn_beta  = (const float*)d_in[10];

    float* ws  = (float*)d_ws;
    float* out = (float*)d_out;

    proj_kernel<<<B_B * TILES, 512, 0, stream>>>(x, g_w, g_b, theta_w, theta_b,
                                                 phi_w, phi_b, ws);
    // DIAGNOSTIC: K3 body repeated 5x inside the kernel to surface counters.
    // K3_per_rep = (dur - 16.9)/4
    out_kernel<<<256, 512, 0, stream>>>(x, w_w, bn_gamma, bn_beta, ws, out);
}

// Round 13
// 17.758 us; speedup vs baseline: 1.9822x; 1.9822x over previous
//
#include <hip/hip_runtime.h>

#define N_SP 2304      // H*W = 48*48
#define C_CH 256
#define B_B  8
#define TILES 36       // N_SP / 64
#define BN_EPS 1e-5f

// workspace layout (float offsets)
#define WS_THETA 0                 // 8*2304 = 18432 floats
#define WS_PG    18432             // 288
#define WS_TH    (18432 + 288)     // 288
#define WS_TH2   (18432 + 576)     // 288

// K1: per-(b, 64-n tile) projections. (byte-identical to R4/R7)
__global__ __launch_bounds__(512) void proj_kernel(
    const float* __restrict__ x,
    const float* __restrict__ gw, const float* __restrict__ gb,
    const float* __restrict__ tw, const float* __restrict__ tb,
    const float* __restrict__ pw, const float* __restrict__ pb,
    float* __restrict__ ws)
{
    __shared__ float pt[8][64], pp[8][64], pgv[8][64];

    const int tid  = threadIdx.x;
    const int w    = tid >> 6;
    const int lane = tid & 63;
    const int blk  = blockIdx.x;
    const int b    = blk / TILES;
    const int tile = blk - b * TILES;

    const int n = tile * 64 + lane;
    const int cbase = __builtin_amdgcn_readfirstlane(w * 32);   // SGPR
    const float* xp = x + (size_t)b * C_CH * N_SP + (size_t)cbase * N_SP + n;

    float at = 0.f, ap = 0.f, ag = 0.f;
    #pragma unroll
    for (int c = 0; c < 32; ++c) {
        float v = xp[(size_t)c * N_SP];           // 256B coalesced per wave
        at = fmaf(tw[cbase + c], v, at);          // s_load (scalar cache)
        ap = fmaf(pw[cbase + c], v, ap);
        ag = fmaf(gw[cbase + c], v, ag);
    }
    pt[w][lane]  = at;
    pp[w][lane]  = ap;
    pgv[w][lane] = ag;
    __syncthreads();

    if (tid < 64) {
        float st = 0.f, sp = 0.f, sg = 0.f;
        #pragma unroll
        for (int j = 0; j < 8; ++j) {
            st += pt[j][tid];
            sp += pp[j][tid];
            sg += pgv[j][tid];
        }
        const float th = st + tb[0];
        const float ph = sp + pb[0];
        const float gg = sg + gb[0];

        ws[WS_THETA + b * N_SP + tile * 64 + tid] = th;

        float r_pg  = ph * gg;
        float r_th  = th;
        float r_th2 = th * th;
        #pragma unroll
        for (int off = 32; off >= 1; off >>= 1) {
            r_pg  += __shfl_xor(r_pg,  off, 64);
            r_th  += __shfl_xor(r_th,  off, 64);
            r_th2 += __shfl_xor(r_th2, off, 64);
        }
        if (tid == 0) {
            ws[WS_PG  + blk] = r_pg;
            ws[WS_TH  + blk] = r_th;
            ws[WS_TH2 + blk] = r_th2;
        }
    }
}

// K3: PREFETCH x/theta rows into registers BEFORE the prologue barrier so
// stream-load latency hides under the finalize; compute + store after.
__global__ __launch_bounds__(512) void out_kernel(
    const float* __restrict__ x,  const float* __restrict__ ww,
    const float* __restrict__ gamma, const float* __restrict__ beta,
    const float* __restrict__ ws, float* __restrict__ out)
{
    __shared__ float fS[B_B], fTH[B_B], fTH2[B_B];
    const int tid = threadIdx.x;

    const int blk  = blockIdx.x;                       // 0..255
    const int b    = blk >> 5;                          // 32 blocks per b
    const int c0   = (blk & 31) * 8;                    // 8 channels per block
    const int w    = __builtin_amdgcn_readfirstlane(tid >> 6);  // wave id
    const int lane = tid & 63;
    const int c    = c0 + w;                            // wave-uniform channel

    const size_t row = ((size_t)b * C_CH + c) * N_SP;
    const float4* xr = (const float4*)(x + row);
    const float4* tr = (const float4*)(ws + WS_THETA + b * N_SP);

    // ---- prefetch the full row (9 x float4 each of x and theta) ----
    float4 xv[9], tv[9];
    #pragma unroll
    for (int k = 0; k < 9; ++k) {
        xv[k] = xr[lane + k * 64];
        tv[k] = tr[lane + k * 64];
    }

    // ---- finalize prologue: wave 0 reduces the 3x288 partials ----
    if (tid < 64) {
        const int fb = tid >> 3;        // 8 groups of 8 lanes
        const int l  = tid & 7;
        float pg = 0.f, th = 0.f, th2 = 0.f;
        #pragma unroll
        for (int k = 0; k < 5; ++k) {
            const int t = l + 8 * k;
            if (t < TILES) {
                pg  += ws[WS_PG  + fb * TILES + t];
                th  += ws[WS_TH  + fb * TILES + t];
                th2 += ws[WS_TH2 + fb * TILES + t];
            }
        }
        #pragma unroll
        for (int off = 4; off >= 1; off >>= 1) {
            pg  += __shfl_xor(pg,  off, 64);
            th  += __shfl_xor(th,  off, 64);
            th2 += __shfl_xor(th2, off, 64);
        }
        if (l == 0) {
            fS[fb]   = pg / (float)N_SP;   // s_b
            fTH[fb]  = th;
            fTH2[fb] = th2;
        }
    }
    __syncthreads();

    float ybar = 0.f, ey2 = 0.f;
    #pragma unroll
    for (int bb = 0; bb < B_B; ++bb) {
        ybar += fS[bb] * fTH[bb];     // LDS broadcast reads
        ey2  += fS[bb] * fS[bb] * fTH2[bb];
    }
    const float inv = 1.0f / (float)(B_B * N_SP);
    ybar *= inv;
    ey2  *= inv;
    const float vary = ey2 - ybar * ybar;

    const float wv = ww[c];          // wave-uniform -> s_load
    const float sc = gamma[c] * wv * rsqrtf(fmaf(wv * wv, vary, BN_EPS));
    const float s  = fS[b];
    const float be = beta[c];
    const float yb = ybar;

    float4* orow = (float4*)((float*)out + row);
    #pragma unroll
    for (int k = 0; k < 9; ++k) {
        float4 o;
        o.x = fmaf(sc, fmaf(tv[k].x, s, -yb), xv[k].x + be);
        o.y = fmaf(sc, fmaf(tv[k].y, s, -yb), xv[k].y + be);
        o.z = fmaf(sc, fmaf(tv[k].z, s, -yb), xv[k].z + be);
        o.w = fmaf(sc, fmaf(tv[k].w, s, -yb), xv[k].w + be);
        orow[lane + k * 64] = o;
    }
}

extern "C" void kernel_launch(void* const* d_in, const int* in_sizes, int n_in,
                              void* d_out, int out_size, void* d_ws, size_t ws_size,
                              hipStream_t stream) {
    const float* x        = (const float*)d_in[0];
    const float* g_w      = (const float*)d_in[1];
    const float* g_b      = (const float*)d_in[2];
    const float* theta_w  = (const float*)d_in[3];
    const float* theta_b  = (const float*)d_in[4];
    const float* phi_w    = (const float*)d_in[5];
    const float* phi_b    = (const float*)d_in[6];
    const float* w_w      = (const float*)d_in[7];
    // d_in[8] = w_b : cancels in training-mode BatchNorm (mean subtraction)
    const float* bn_gamma = (const float*)d_in[9];
    const float* bn_beta  = (const float*)d_in[10];

    float* ws  = (float*)d_ws;
    float* out = (float*)d_out;

    proj_kernel<<<B_B * TILES, 512, 0, stream>>>(x, g_w, g_b, theta_w, theta_b,
                                                 phi_w, phi_b, ws);
    out_kernel<<<256, 512, 0, stream>>>(x, w_w, bn_gamma, bn_beta, ws, out);
}

// Round 14
// 16.783 us; speedup vs baseline: 2.0973x; 1.0581x over previous
//
#include <hip/hip_runtime.h>

#define N_SP 2304      // H*W = 48*48
#define C_CH 256
#define B_B  8
#define TILES 36       // N_SP / 64
#define BN_EPS 1e-5f

// workspace layout (float offsets)
#define WS_THETA 0                 // 8*2304 = 18432 floats
#define WS_PG    18432             // 288
#define WS_TH    (18432 + 288)     // 288
#define WS_TH2   (18432 + 576)     // 288

// K1: per-(b, 64-n tile) projections. 8 waves each own a 32-channel chunk.
// (byte-identical to the measured-best R7 version)
__global__ __launch_bounds__(512) void proj_kernel(
    const float* __restrict__ x,
    const float* __restrict__ gw, const float* __restrict__ gb,
    const float* __restrict__ tw, const float* __restrict__ tb,
    const float* __restrict__ pw, const float* __restrict__ pb,
    float* __restrict__ ws)
{
    __shared__ float pt[8][64], pp[8][64], pgv[8][64];

    const int tid  = threadIdx.x;
    const int w    = tid >> 6;
    const int lane = tid & 63;
    const int blk  = blockIdx.x;
    const int b    = blk / TILES;
    const int tile = blk - b * TILES;

    const int n = tile * 64 + lane;
    const int cbase = __builtin_amdgcn_readfirstlane(w * 32);   // SGPR
    const float* xp = x + (size_t)b * C_CH * N_SP + (size_t)cbase * N_SP + n;

    float at = 0.f, ap = 0.f, ag = 0.f;
    #pragma unroll
    for (int c = 0; c < 32; ++c) {
        float v = xp[(size_t)c * N_SP];           // 256B coalesced per wave
        at = fmaf(tw[cbase + c], v, at);          // s_load (scalar cache)
        ap = fmaf(pw[cbase + c], v, ap);
        ag = fmaf(gw[cbase + c], v, ag);
    }
    pt[w][lane]  = at;
    pp[w][lane]  = ap;
    pgv[w][lane] = ag;
    __syncthreads();

    if (tid < 64) {
        float st = 0.f, sp = 0.f, sg = 0.f;
        #pragma unroll
        for (int j = 0; j < 8; ++j) {
            st += pt[j][tid];
            sp += pp[j][tid];
            sg += pgv[j][tid];
        }
        const float th = st + tb[0];
        const float ph = sp + pb[0];
        const float gg = sg + gb[0];

        ws[WS_THETA + b * N_SP + tile * 64 + tid] = th;

        float r_pg  = ph * gg;
        float r_th  = th;
        float r_th2 = th * th;
        #pragma unroll
        for (int off = 32; off >= 1; off >>= 1) {
            r_pg  += __shfl_xor(r_pg,  off, 64);
            r_th  += __shfl_xor(r_th,  off, 64);
            r_th2 += __shfl_xor(r_th2, off, 64);
        }
        if (tid == 0) {
            ws[WS_PG  + blk] = r_pg;
            ws[WS_TH  + blk] = r_th;
            ws[WS_TH2 + blk] = r_th2;
        }
    }
}

// K3: 256 blocks x 512 threads; one finalize prologue per block (wave 0),
// then each WAVE streams one full (b,c) row. (byte-identical to R7)
__global__ __launch_bounds__(512) void out_kernel(
    const float* __restrict__ x,  const float* __restrict__ ww,
    const float* __restrict__ gamma, const float* __restrict__ beta,
    const float* __restrict__ ws, float* __restrict__ out)
{
    __shared__ float fS[B_B], fTH[B_B], fTH2[B_B];
    const int tid = threadIdx.x;

    // ---- finalize prologue: wave 0 reduces the 3x288 partials ----
    if (tid < 64) {
        const int fb = tid >> 3;        // 8 groups of 8 lanes
        const int l  = tid & 7;
        float pg = 0.f, th = 0.f, th2 = 0.f;
        #pragma unroll
        for (int k = 0; k < 5; ++k) {
            const int t = l + 8 * k;
            if (t < TILES) {
                pg  += ws[WS_PG  + fb * TILES + t];
                th  += ws[WS_TH  + fb * TILES + t];
                th2 += ws[WS_TH2 + fb * TILES + t];
            }
        }
        #pragma unroll
        for (int off = 4; off >= 1; off >>= 1) {
            pg  += __shfl_xor(pg,  off, 64);
            th  += __shfl_xor(th,  off, 64);
            th2 += __shfl_xor(th2, off, 64);
        }
        if (l == 0) {
            fS[fb]   = pg / (float)N_SP;   // s_b
            fTH[fb]  = th;
            fTH2[fb] = th2;
        }
    }
    __syncthreads();

    const int blk  = blockIdx.x;                       // 0..255
    const int b    = blk >> 5;                          // 32 blocks per b
    const int c0   = (blk & 31) * 8;                    // 8 channels per block
    const int w    = __builtin_amdgcn_readfirstlane(tid >> 6);  // wave id
    const int lane = tid & 63;
    const int c    = c0 + w;                            // wave-uniform channel

    float ybar = 0.f, ey2 = 0.f;
    #pragma unroll
    for (int bb = 0; bb < B_B; ++bb) {
        ybar += fS[bb] * fTH[bb];     // LDS broadcast reads
        ey2  += fS[bb] * fS[bb] * fTH2[bb];
    }
    const float inv = 1.0f / (float)(B_B * N_SP);
    ybar *= inv;
    ey2  *= inv;
    const float vary = ey2 - ybar * ybar;

    const float wv = ww[c];          // wave-uniform -> s_load
    const float sc = gamma[c] * wv * rsqrtf(fmaf(wv * wv, vary, BN_EPS));
    const float s  = fS[b];
    const float be = beta[c];
    const float yb = ybar;

    const size_t row = ((size_t)b * C_CH + c) * N_SP;
    const float4* xr   = (const float4*)(x + row);
    const float4* tr   = (const float4*)(ws + WS_THETA + b * N_SP);
    float4*       orow = (float4*)((float*)out + row);

    #pragma unroll
    for (int k = 0; k < 9; ++k) {
        const int i = lane + k * 64;   // 9*64*4 = 2304 floats exactly
        float4 xv = xr[i];
        float4 tv = tr[i];
        float4 o;
        o.x = fmaf(sc, fmaf(tv.x, s, -yb), xv.x + be);
        o.y = fmaf(sc, fmaf(tv.y, s, -yb), xv.y + be);
        o.z = fmaf(sc, fmaf(tv.z, s, -yb), xv.z + be);
        o.w = fmaf(sc, fmaf(tv.w, s, -yb), xv.w + be);
        orow[i] = o;
    }
}

extern "C" void kernel_launch(void* const* d_in, const int* in_sizes, int n_in,
                              void* d_out, int out_size, void* d_ws, size_t ws_size,
                              hipStream_t stream) {
    const float* x        = (const float*)d_in[0];
    const float* g_w      = (const float*)d_in[1];
    const float* g_b      = (const float*)d_in[2];
    const float* theta_w  = (const float*)d_in[3];
    const float* theta_b  = (const float*)d_in[4];
    const float* phi_w    = (const float*)d_in[5];
    const float* phi_b    = (const float*)d_in[6];
    const float* w_w      = (const float*)d_in[7];
    // d_in[8] = w_b : cancels in training-mode BatchNorm (mean subtraction)
    const float* bn_gamma = (const float*)d_in[9];
    const float* bn_beta  = (const float*)d_in[10];

    float* ws  = (float*)d_ws;
    float* out = (float*)d_out;

    proj_kernel<<<B_B * TILES, 512, 0, stream>>>(x, g_w, g_b, theta_w, theta_b,
                                                 phi_w, phi_b, ws);
    out_kernel<<<256, 512, 0, stream>>>(x, w_w, bn_gamma, bn_beta, ws, out);
}